// Round 3
// baseline (316.357 us; speedup 1.0000x reference)
//
#include <hip/hip_runtime.h>

// Problem constants
#define B_    4
#define L_    1024
#define D_    768
#define H_    12
#define NE_   42
#define M_    8
#define NE2_  (NE_ * NE_)   // 1764
#define MPAD_ 1792          // 1764 padded up to 14*128 for clean GEMM tiles

typedef unsigned short u16;
typedef unsigned int   u32;

__device__ __forceinline__ u16 f2bf(float f) {
    union { float f; u32 u; } c; c.f = f;
    u32 u = c.u;
    u32 r = (u + 0x7FFFu + ((u >> 16) & 1u)) >> 16;  // round-to-nearest-even
    return (u16)r;
}

// ---------------------------------------------------------------------------
// Kernel 1: ent_att[b,h,e,l] = (1/cnt) * sum_{valid m} attention[b,h,idx[b,e,m]+1,l]
// attention is f32 [B,H,L,L]. grid (H, NE, B), 128 threads;
// thread t covers l = t*8 .. t*8+7 (two float4 loads per mention row)
// ---------------------------------------------------------------------------
__global__ __launch_bounds__(128) void ent_att_kernel(
    const float* __restrict__ att, const int* __restrict__ midx,
    const int* __restrict__ mmask, float* __restrict__ ent) {
    const int h = blockIdx.x, e = blockIdx.y, b = blockIdx.z;
    const int t  = threadIdx.x;
    const int l0 = t * 8;
    const int mb = (b * NE_ + e) * M_;
    const size_t abase = ((size_t)(b * H_ + h)) * L_ * L_;

    float acc[8] = {0.f,0.f,0.f,0.f,0.f,0.f,0.f,0.f};
    int cnt = 0;
    for (int m = 0; m < M_; ++m) {
        int  im = midx[mb + m] + 1;                       // OFFSET = 1
        bool v  = (mmask[mb + m] > 0) && (im < L_);
        if (v) {
            ++cnt;
            const float* row = att + abase + (size_t)im * L_ + l0;
            float4 x0 = *(const float4*)(row);
            float4 x1 = *(const float4*)(row + 4);
            acc[0] += x0.x; acc[1] += x0.y; acc[2] += x0.z; acc[3] += x0.w;
            acc[4] += x1.x; acc[5] += x1.y; acc[6] += x1.z; acc[7] += x1.w;
        }
    }
    const float s = 1.0f / (float)(cnt < 1 ? 1 : cnt);
    float* o = ent + (((size_t)(b * H_ + h)) * NE_ + e) * L_ + l0;
    *(float4*)(o)     = make_float4(acc[0]*s, acc[1]*s, acc[2]*s, acc[3]*s);
    *(float4*)(o + 4) = make_float4(acc[4]*s, acc[5]*s, acc[6]*s, acc[7]*s);
}

// ---------------------------------------------------------------------------
// Kernel 2: transpose+convert sequence_output f32 [b][k=L][n=D] -> ST bf16
// [b][n=D][k=L], so the GEMM B-operand fragment (8 contiguous k per lane)
// is a ds_read_b128. grid (D/32, L/32, B), block (32,8)
// ---------------------------------------------------------------------------
__global__ __launch_bounds__(256) void transpose_kernel(
    const float* __restrict__ S, u16* __restrict__ T) {
    __shared__ u16 tile[32][33];
    const int b  = blockIdx.z;
    const int n0 = blockIdx.x * 32;
    const int k0 = blockIdx.y * 32;
    const int tx = threadIdx.x, ty = threadIdx.y;
    const float* Sb = S + (size_t)b * L_ * D_;
    u16*         Tb = T + (size_t)b * D_ * L_;
    #pragma unroll
    for (int i = 0; i < 4; ++i)
        tile[ty + i*8][tx] = f2bf(Sb[(size_t)(k0 + ty + i*8) * D_ + (n0 + tx)]);
    __syncthreads();
    #pragma unroll
    for (int i = 0; i < 4; ++i)
        Tb[(size_t)(n0 + ty + i*8) * L_ + (k0 + tx)] = tile[tx][ty + i*8];
}

// ---------------------------------------------------------------------------
// Kernel 3: W[b][p][l] (bf16), p = s*NE+t:
//   acc_l = sum_h ent[b,h,s,l]*ent[b,h,t,l]
//   w_l   = acc_l / (rowsum(acc) + H*1e-5)      (== (acc/H)/(sum(acc/H)+1e-5))
// Rows p in [1764,1792) are zero padding for the GEMM.
// grid (B*MPAD_), 128 threads; thread t covers l = t*8..t*8+7
// ---------------------------------------------------------------------------
__global__ __launch_bounds__(128) void w_kernel(
    const float* __restrict__ ent, u16* __restrict__ W) {
    const int p = blockIdx.x % MPAD_;
    const int b = blockIdx.x / MPAD_;
    const int t  = threadIdx.x;
    const int l0 = t * 8;
    u16* wrow = W + ((size_t)b * MPAD_ + p) * L_;

    if (p >= NE2_) {                       // zero pad rows (ws is poisoned!)
        uint4 z; z.x = z.y = z.z = z.w = 0u;
        *(uint4*)(wrow + l0) = z;
        return;
    }
    const int s  = p / NE_;
    const int tt = p % NE_;
    const float* Eb = ent + (size_t)b * H_ * NE_ * L_;

    float acc[8] = {0.f,0.f,0.f,0.f,0.f,0.f,0.f,0.f};
    for (int h = 0; h < H_; ++h) {
        const float4* as = (const float4*)(Eb + ((size_t)(h * NE_ + s))  * L_ + l0);
        const float4* at = (const float4*)(Eb + ((size_t)(h * NE_ + tt)) * L_ + l0);
        float4 a0 = as[0], a1 = as[1], b0 = at[0], b1 = at[1];
        acc[0] += a0.x * b0.x; acc[1] += a0.y * b0.y;
        acc[2] += a0.z * b0.z; acc[3] += a0.w * b0.w;
        acc[4] += a1.x * b1.x; acc[5] += a1.y * b1.y;
        acc[6] += a1.z * b1.z; acc[7] += a1.w * b1.w;
    }
    float local = acc[0]+acc[1]+acc[2]+acc[3]+acc[4]+acc[5]+acc[6]+acc[7];
    #pragma unroll
    for (int off = 32; off > 0; off >>= 1) local += __shfl_xor(local, off, 64);
    __shared__ float red[2];
    const int wv = t >> 6, ln = t & 63;
    if (ln == 0) red[wv] = local;
    __syncthreads();
    const float tot = red[0] + red[1];
    const float inv = 1.0f / (tot + (float)H_ * 1e-5f);

    u32 w0 = (u32)f2bf(acc[0]*inv) | ((u32)f2bf(acc[1]*inv) << 16);
    u32 w1 = (u32)f2bf(acc[2]*inv) | ((u32)f2bf(acc[3]*inv) << 16);
    u32 w2 = (u32)f2bf(acc[4]*inv) | ((u32)f2bf(acc[5]*inv) << 16);
    u32 w3 = (u32)f2bf(acc[6]*inv) | ((u32)f2bf(acc[7]*inv) << 16);
    uint4 o; o.x = w0; o.y = w1; o.z = w2; o.w = w3;
    *(uint4*)(wrow + l0) = o;
}

// ---------------------------------------------------------------------------
// Kernel 4: batched GEMM out[b] = W[b] (MPADx1024) @ S[b] (1024x768), bf16 MFMA,
// f32 output. Both operands stored [row][k]. 128x128x32 tiles, 256 thr =
// 4 waves in 2x2, each wave a 64x64 quadrant of 4x4 16x16x32 MFMAs.
// Staging via global_load_lds width=16 (m97 pattern).
// grid (MPAD/128=14, D/128=6, B)
// ---------------------------------------------------------------------------
typedef __attribute__((ext_vector_type(8))) __bf16 bf16x8;
typedef __attribute__((ext_vector_type(4))) float  f32x4;

__global__ __launch_bounds__(256) void gemm_kernel(
    const u16* __restrict__ W, const u16* __restrict__ T, float* __restrict__ out) {
    __shared__ __align__(16) u16 As[128 * 32];
    __shared__ __align__(16) u16 Bs[128 * 32];
    const int b = blockIdx.z;
    const u16* Ab = W + (size_t)b * MPAD_ * L_ + (size_t)blockIdx.x * 128 * L_;
    const u16* Bb = T + (size_t)b * D_   * L_ + (size_t)blockIdx.y * 128 * L_;
    const int tid  = threadIdx.x;
    const int wave = tid >> 6, lane = tid & 63;
    const int wm = (wave & 1) * 64, wn = (wave >> 1) * 64;
    const int rm = lane & 15, kq = (lane >> 4) * 8;

    f32x4 acc[4][4] = {};

    for (int k0 = 0; k0 < L_; k0 += 32) {
        __syncthreads();   // prior iteration's frag reads done before overwrite
        #pragma unroll
        for (int i = 0; i < 2; ++i) {
            int c = i * 256 + tid;            // 512 chunks of 16B = 8KB tile
            int row = c >> 2, ko = (c & 3) * 8;
            __builtin_amdgcn_global_load_lds(
                (const __attribute__((address_space(1))) void*)(Ab + (size_t)row * L_ + k0 + ko),
                (__attribute__((address_space(3))) void*)(&As[c * 8]), 16, 0, 0);
            __builtin_amdgcn_global_load_lds(
                (const __attribute__((address_space(1))) void*)(Bb + (size_t)row * L_ + k0 + ko),
                (__attribute__((address_space(3))) void*)(&Bs[c * 8]), 16, 0, 0);
        }
        __syncthreads();   // drains vmcnt (global_load_lds) per barrier semantics

        bf16x8 af[4], bfr[4];
        #pragma unroll
        for (int i = 0; i < 4; ++i)
            af[i]  = *(const bf16x8*)&As[(wm + i*16 + rm) * 32 + kq];
        #pragma unroll
        for (int j = 0; j < 4; ++j)
            bfr[j] = *(const bf16x8*)&Bs[(wn + j*16 + rm) * 32 + kq];
        #pragma unroll
        for (int i = 0; i < 4; ++i)
            #pragma unroll
            for (int j = 0; j < 4; ++j)
                acc[i][j] = __builtin_amdgcn_mfma_f32_16x16x32_bf16(
                                af[i], bfr[j], acc[i][j], 0, 0, 0);
    }

    // Epilogue: C/D layout col = lane&15, row = (lane>>4)*4 + reg (m89/m91)
    // Output is FLOAT32.
    const int row0 = blockIdx.x * 128 + wm;
    const int col0 = blockIdx.y * 128 + wn;
    const int cl = lane & 15, rq = (lane >> 4) * 4;
    float* Ob = out + (size_t)b * NE2_ * D_;
    #pragma unroll
    for (int i = 0; i < 4; ++i) {
        #pragma unroll
        for (int j = 0; j < 4; ++j) {
            const int col = col0 + j*16 + cl;
            #pragma unroll
            for (int r = 0; r < 4; ++r) {
                const int row = row0 + i*16 + rq + r;
                if (row < NE2_)
                    Ob[(size_t)row * D_ + col] = acc[i][j][r];
            }
        }
    }
}

// ---------------------------------------------------------------------------
// Workspace layout (bytes):
//   ent : f32 [B][H][NE][L]   =  8,257,536
//   W   : bf16 [B][MPAD][L]   = 14,680,064
//   ST  : bf16 [B][D][L]      =  6,291,456
// total ~29.2 MB
// ---------------------------------------------------------------------------
#define ENT_BYTES (8257536)
#define W_BYTES   (14680064)

extern "C" void kernel_launch(void* const* d_in, const int* in_sizes, int n_in,
                              void* d_out, int out_size, void* d_ws, size_t ws_size,
                              hipStream_t stream) {
    const float* seq   = (const float*)d_in[0];   // [B,L,D]  f32
    const float* att   = (const float*)d_in[1];   // [B,H,L,L] f32
    const int*   midx  = (const int*)d_in[2];     // [B,NE,M]
    const int*   mmask = (const int*)d_in[3];     // [B,NE,M]
    float* out = (float*)d_out;                   // [B,NE,NE,D] f32

    char* ws  = (char*)d_ws;
    float* ent = (float*)ws;
    u16*   W   = (u16*)(ws + ENT_BYTES);
    u16*   ST  = (u16*)(ws + ENT_BYTES + W_BYTES);

    ent_att_kernel<<<dim3(H_, NE_, B_), 128, 0, stream>>>(att, midx, mmask, ent);
    transpose_kernel<<<dim3(D_/32, L_/32, B_), dim3(32, 8), 0, stream>>>(seq, ST);
    w_kernel<<<B_ * MPAD_, 128, 0, stream>>>(ent, W);
    gemm_kernel<<<dim3(MPAD_/128, D_/128, B_), 256, 0, stream>>>(W, ST, out);
}